// Round 3
// baseline (15104.509 us; speedup 1.0000x reference)
//
#include <hip/hip_runtime.h>
#include <stdint.h>
#include <math.h>

#define NB 512
#define NS 200
#define NH 128
#define NH3 384

// ---------------- XLA-exact scalar helpers ----------------
__device__ __forceinline__ float xla_tanhf(float x) {
  float cx = fminf(fmaxf(x, -9.0f), 9.0f);
  float x2 = __fmul_rn(cx, cx);
  float p = -2.76076847742355e-16f;
  p = __fadd_rn(__fmul_rn(x2, p), 2.00018790482477e-13f);
  p = __fadd_rn(__fmul_rn(x2, p), -8.60467152213735e-11f);
  p = __fadd_rn(__fmul_rn(x2, p), 5.12229709037114e-08f);
  p = __fadd_rn(__fmul_rn(x2, p), 1.48572235717979e-05f);
  p = __fadd_rn(__fmul_rn(x2, p), 6.37261928875436e-04f);
  p = __fadd_rn(__fmul_rn(x2, p), 4.89352455891786e-03f);
  p = __fmul_rn(cx, p);
  float q = 1.19825839466702e-06f;
  q = __fadd_rn(__fmul_rn(x2, q), 1.18534705686654e-04f);
  q = __fadd_rn(__fmul_rn(x2, q), 2.26843463243900e-03f);
  q = __fadd_rn(__fmul_rn(x2, q), 4.89352518554385e-03f);
  float r = __fdiv_rn(p, q);
  return (fabsf(x) < 0.0004f) ? x : r;
}

__device__ __forceinline__ float xla_sigmoidf(float x) {
  return __fadd_rn(0.5f, __fmul_rn(0.5f, xla_tanhf(__fmul_rn(0.5f, x))));
}

__device__ __forceinline__ uint32_t rotl32(uint32_t v, int r) {
  return (v << r) | (v >> (32 - r));
}
__device__ __forceinline__ void threefry2x32(uint32_t k0, uint32_t k1,
                                             uint32_t x0, uint32_t x1,
                                             uint32_t& o0, uint32_t& o1) {
  uint32_t k2 = k0 ^ k1 ^ 0x1BD11BDAu;
  x0 += k0; x1 += k1;
  #define TFR(r) { x0 += x1; x1 = rotl32(x1, r); x1 ^= x0; }
  TFR(13) TFR(15) TFR(26) TFR(6)
  x0 += k1; x1 += k2 + 1u;
  TFR(17) TFR(29) TFR(16) TFR(24)
  x0 += k2; x1 += k0 + 2u;
  TFR(13) TFR(15) TFR(26) TFR(6)
  x0 += k0; x1 += k1 + 3u;
  TFR(17) TFR(29) TFR(16) TFR(24)
  x0 += k1; x1 += k2 + 4u;
  TFR(13) TFR(15) TFR(26) TFR(6)
  x0 += k2; x1 += k0 + 5u;
  #undef TFR
  o0 = x0; o1 = x1;
}

__device__ __forceinline__ float bits_to_gumbel(uint32_t bits) {
  const float kTiny = 1.1754943508222875e-38f;
  float f = __fsub_rn(__uint_as_float((bits >> 9) | 0x3F800000u), 1.0f);
  float u = __fadd_rn(__fmul_rn(f, __fsub_rn(1.0f, kTiny)), kTiny);
  u = fmaxf(kTiny, u);
  return -logf(-logf(u));
}

// ---------------- persistent whole-decode kernel: 1 block per batch row ----
__global__ __launch_bounds__(256, 1) void k_decode(
    const float* __restrict__ stat, const float* __restrict__ dyn,
    const float* __restrict__ sW,   const float* __restrict__ sb,
    const float* __restrict__ dW,   const float* __restrict__ db,
    const float* __restrict__ x0,   const float* __restrict__ h0,
    const float* __restrict__ Wemb, const float* __restrict__ bemb,
    const float* __restrict__ Wih,  const float* __restrict__ Whh,
    const float* __restrict__ bih,  const float* __restrict__ bhh,
    const float* __restrict__ Wa,   const float* __restrict__ va,
    const float* __restrict__ Wd,   const float* __restrict__ vd,
    float* __restrict__ out) {

  __shared__ float WaHT[NH][130];          // Wa[:,256+k] transposed: WaHT[k][h]
  __shared__ __align__(16) float st0L[NS], st1L[NS], dy0L[NS], dy1L[NS];
  __shared__ float As0[NH], As1[NH], Ad0[NH], Ad1[NH], Ac[NH];
  __shared__ float Ds0[NH], Ds1[NH], Dc[NH], Cw0[NH], Cw1[NH], Cwb[NH];
  __shared__ float vaL[NH], vdL[NH];
  __shared__ float WembL[2*NH], bembL[NH];
  __shared__ float bihL[NH3], bhhL[NH3];
  __shared__ __align__(16) float embL[NH], hL[NH];
  __shared__ float hnL[NH], HtL[NH];
  __shared__ float giL[NH3], ghL[NH3];
  __shared__ float sc[NS], ex[NS], at[NS];
  __shared__ float red[256];
  __shared__ int ri[256];
  __shared__ uint32_t keysL[2*NS];
  __shared__ float xpL[2];
  __shared__ float Rv[4];

  const int t = threadIdx.x;
  const int b = blockIdx.x;

  // ---- one-time setup ----
  // register-resident GRU weight rows: dot d = t + 256*i, d<384 -> Wih row d,
  // else Whh row d-384.
  float4 w0[32], w1[32], w2[32];
  {
    const float4* p0 = (const float4*)(Wih + (size_t)t * NH);
    const float4* p1 = (t < NH)
        ? (const float4*)(Wih + (size_t)(256 + t) * NH)
        : (const float4*)(Whh + (size_t)(t - NH) * NH);
    const float4* p2 = (const float4*)(Whh + (size_t)(t + NH) * NH);
    #pragma unroll
    for (int k4 = 0; k4 < 32; ++k4) { w0[k4] = p0[k4]; w1[k4] = p1[k4]; w2[k4] = p2[k4]; }
  }

  // static/dynamic rows for this b
  if (t < NS) {
    st0L[t] = stat[(size_t)b*2*NS + t];
    st1L[t] = stat[(size_t)b*2*NS + NS + t];
    dy0L[t] = dyn[(size_t)b*2*NS + t];
    dy1L[t] = dyn[(size_t)b*2*NS + NS + t];
  }
  // folded attention/decoder vectors (identical math to round-2 k_pre)
  if (t < NH) {
    int h = t;
    const float* war = Wa + (size_t)h * NH3;
    float as0 = 0.f, as1 = 0.f, ad0 = 0.f, ad1 = 0.f, ac = 0.f;
    for (int k = 0; k < NH; ++k) {
      as0 = fmaf(war[k],     sW[k*2+0], as0);
      as1 = fmaf(war[k],     sW[k*2+1], as1);
      ad0 = fmaf(war[NH+k],  dW[k*2+0], ad0);
      ad1 = fmaf(war[NH+k],  dW[k*2+1], ad1);
      ac  = fmaf(war[k],     sb[k],     ac);
    }
    for (int k = 0; k < NH; ++k) ac = fmaf(war[NH+k], db[k], ac);
    As0[h] = as0; As1[h] = as1; Ad0[h] = ad0; Ad1[h] = ad1; Ac[h] = ac;

    const float* wdr = Wd + (size_t)h * 256;
    float ds0 = 0.f, ds1 = 0.f, dc = 0.f, c0 = 0.f, c1 = 0.f, cb = 0.f;
    for (int k = 0; k < NH; ++k) {
      ds0 = fmaf(wdr[k],    sW[k*2+0], ds0);
      ds1 = fmaf(wdr[k],    sW[k*2+1], ds1);
      dc  = fmaf(wdr[k],    sb[k],     dc);
      c0  = fmaf(wdr[NH+k], sW[k*2+0], c0);
      c1  = fmaf(wdr[NH+k], sW[k*2+1], c1);
      cb  = fmaf(wdr[NH+k], sb[k],     cb);
    }
    Ds0[h] = ds0; Ds1[h] = ds1; Dc[h] = dc;
    Cw0[h] = c0;  Cw1[h] = c1;  Cwb[h] = cb;

    vaL[h] = va[h]; vdL[h] = vd[h];
    bembL[h] = bemb[h];
    WembL[2*h]   = Wemb[2*h];
    WembL[2*h+1] = Wemb[2*h+1];
    hL[h] = h0[h];
  }
  if (t < NS) {
    uint32_t q0, q1;
    threefry2x32(0u, 42u, 0u, (uint32_t)t, q0, q1);
    keysL[2*t] = q0; keysL[2*t + 1] = q1;
  }
  for (int i = t; i < NH3; i += 256) { bihL[i] = bih[i]; bhhL[i] = bhh[i]; }
  for (int i = t; i < NH*NH; i += 256) {
    int k = i >> 7, h = i & 127;
    WaHT[k][h] = Wa[(size_t)h*NH3 + 2*NH + k];
  }
  if (t == 0) { xpL[0] = x0[0]; xpL[1] = x0[1]; }
  __syncthreads();

  // ---- 200 decode steps ----
  for (int step = 0; step < NS; ++step) {
    // S0: emb = x @ Wemb^T + bemb
    if (t < NH) {
      float e = fmaf(xpL[1], WembL[t*2+1], __fmul_rn(xpL[0], WembL[t*2+0]));
      embL[t] = __fadd_rn(e, bembL[t]);
    }
    __syncthreads();

    // S1: gi/gh dots (register weights, LDS broadcast operands; exact
    // sequential-k single-acc fma order per dot)
    {
      const float4* e4 = (const float4*)embL;
      const float4* h4 = (const float4*)hL;
      float a0 = 0.f, a1 = 0.f, a2 = 0.f;
      #define GRU_DOT(SVSEL)                                             \
        _Pragma("unroll")                                                \
        for (int k4 = 0; k4 < 32; ++k4) {                                \
          float4 ev = e4[k4]; float4 hv = h4[k4]; float4 sv = SVSEL;     \
          a0 = fmaf(w0[k4].x, ev.x, a0); a0 = fmaf(w0[k4].y, ev.y, a0);  \
          a0 = fmaf(w0[k4].z, ev.z, a0); a0 = fmaf(w0[k4].w, ev.w, a0);  \
          a1 = fmaf(w1[k4].x, sv.x, a1); a1 = fmaf(w1[k4].y, sv.y, a1);  \
          a1 = fmaf(w1[k4].z, sv.z, a1); a1 = fmaf(w1[k4].w, sv.w, a1);  \
          a2 = fmaf(w2[k4].x, hv.x, a2); a2 = fmaf(w2[k4].y, hv.y, a2);  \
          a2 = fmaf(w2[k4].z, hv.z, a2); a2 = fmaf(w2[k4].w, hv.w, a2);  \
        }
      if (t < NH) { GRU_DOT(ev) } else { GRU_DOT(hv) }
      #undef GRU_DOT
      giL[t] = __fadd_rn(a0, bihL[t]);
      if (t < NH) giL[256 + t]  = __fadd_rn(a1, bihL[256 + t]);
      else        ghL[t - NH]   = __fadd_rn(a1, bhhL[t - NH]);
      ghL[t + NH] = __fadd_rn(a2, bhhL[t + NH]);
    }
    __syncthreads();

    // S2: gates (torch order r,z,n), h_new
    if (t < NH) {
      float r = xla_sigmoidf(__fadd_rn(giL[t],        ghL[t]));
      float z = xla_sigmoidf(__fadd_rn(giL[t+NH],     ghL[t+NH]));
      float n = xla_tanhf(__fadd_rn(giL[t+2*NH], __fmul_rn(r, ghL[t+2*NH])));
      float hv = hL[t];
      hnL[t] = __fadd_rn(__fmul_rn(__fsub_rn(1.0f, z), n), __fmul_rn(z, hv));
    }
    __syncthreads();

    // S3: Hterm = Wa[:,256:384] @ h_new (ascending-k single acc)
    if (t < NH) {
      float acc = 0.f;
      for (int k = 0; k < NH; ++k) acc = fmaf(WaHT[k][t], hnL[k], acc);
      HtL[t] = acc;
    }
    __syncthreads();

    // S4: attention scores
    if (t < NS) {
      float s0 = st0L[t], s1 = st1L[t], d0 = dy0L[t], d1 = dy1L[t];
      float acc = 0.f;
      for (int h = 0; h < NH; ++h) {
        float e = fmaf(As1[h], s1, __fmul_rn(As0[h], s0));
        e = fmaf(Ad0[h], d0, e);
        e = fmaf(Ad1[h], d1, e);
        e = __fadd_rn(e, Ac[h]);
        e = __fadd_rn(e, HtL[h]);
        acc = fmaf(vaL[h], xla_tanhf(e), acc);
      }
      sc[t] = acc;
    }
    __syncthreads();

    // attention softmax
    red[t] = (t < NS) ? sc[t] : -INFINITY; __syncthreads();
    for (int o = 128; o > 0; o >>= 1) { if (t < o) red[t] = fmaxf(red[t], red[t+o]); __syncthreads(); }
    float m = red[0]; __syncthreads();
    if (t < NS) ex[t] = expf(__fsub_rn(sc[t], m));
    __syncthreads();
    red[t] = (t < NS) ? ex[t] : 0.f; __syncthreads();
    for (int o = 128; o > 0; o >>= 1) { if (t < o) red[t] = __fadd_rn(red[t], red[t+o]); __syncthreads(); }
    float sume = red[0]; __syncthreads();
    if (t < NS) at[t] = __fdiv_rn(ex[t], sume);
    __syncthreads();

    // context reductions
    red[t] = (t < NS) ? __fmul_rn(at[t], st0L[t]) : 0.f; __syncthreads();
    for (int o = 128; o > 0; o >>= 1) { if (t < o) red[t] = __fadd_rn(red[t], red[t+o]); __syncthreads(); }
    if (t == 0) Rv[0] = red[0]; __syncthreads();
    red[t] = (t < NS) ? __fmul_rn(at[t], st1L[t]) : 0.f; __syncthreads();
    for (int o = 128; o > 0; o >>= 1) { if (t < o) red[t] = __fadd_rn(red[t], red[t+o]); __syncthreads(); }
    if (t == 0) Rv[1] = red[0]; __syncthreads();
    red[t] = (t < NS) ? at[t] : 0.f; __syncthreads();
    for (int o = 128; o > 0; o >>= 1) { if (t < o) red[t] = __fadd_rn(red[t], red[t+o]); __syncthreads(); }
    if (t == 0) Rv[2] = red[0]; __syncthreads();

    // Cterm
    if (t < NH)
      HtL[t] = fmaf(Rv[0], Cw0[t], fmaf(Rv[1], Cw1[t], __fmul_rn(Rv[2], Cwb[t])));
    __syncthreads();

    // S5: decoder logits
    if (t < NS) {
      float s0 = st0L[t], s1 = st1L[t];
      float acc = 0.f;
      for (int h = 0; h < NH; ++h) {
        float d = fmaf(Ds1[h], s1, __fmul_rn(Ds0[h], s0));
        d = __fadd_rn(d, Dc[h]);
        d = __fadd_rn(d, HtL[h]);
        acc = fmaf(vdL[h], xla_tanhf(d), acc);
      }
      sc[t] = acc;
    }
    __syncthreads();

    // probs softmax
    red[t] = (t < NS) ? sc[t] : -INFINITY; __syncthreads();
    for (int o = 128; o > 0; o >>= 1) { if (t < o) red[t] = fmaxf(red[t], red[t+o]); __syncthreads(); }
    float m2 = red[0]; __syncthreads();
    if (t < NS) ex[t] = expf(__fsub_rn(sc[t], m2));
    __syncthreads();
    red[t] = (t < NS) ? ex[t] : 0.f; __syncthreads();
    for (int o = 128; o > 0; o >>= 1) { if (t < o) red[t] = __fadd_rn(red[t], red[t+o]); __syncthreads(); }
    float sume2 = red[0]; __syncthreads();

    // gumbel-max sampling (partitionable threefry, bit-exact)
    uint32_t k0 = keysL[2*step], k1 = keysL[2*step + 1];
    float gv = -INFINITY;
    if (t < NS) {
      uint32_t j = (uint32_t)(b*NS + t);
      uint32_t q0, q1;
      threefry2x32(k0, k1, 0u, j, q0, q1);
      gv = __fadd_rn(bits_to_gumbel(q0 ^ q1), sc[t]);
    }
    red[t] = gv; ri[t] = t; __syncthreads();
    for (int o = 128; o > 0; o >>= 1) {
      if (t < o) {
        float v2 = red[t+o]; int i2 = ri[t+o];
        if (v2 > red[t] || (v2 == red[t] && i2 < ri[t])) { red[t] = v2; ri[t] = i2; }
      }
      __syncthreads();
    }
    if (t == 0) {
      int widx = ri[0];
      out[(size_t)b*NS + step] = (float)widx;
      out[(size_t)NB*NS + (size_t)b*NS + step] = __fdiv_rn(ex[widx], sume2);
      xpL[0] = st0L[widx];
      xpL[1] = st1L[widx];
    }
    if (t < NH) hL[t] = hnL[t];
    __syncthreads();
  }
}

// ---------------- host launch ----------------
extern "C" void kernel_launch(void* const* d_in, const int* in_sizes, int n_in,
                              void* d_out, int out_size, void* d_ws, size_t ws_size,
                              hipStream_t stream) {
  (void)in_sizes; (void)n_in; (void)out_size; (void)d_ws; (void)ws_size;
  const float* stat = (const float*)d_in[0];
  const float* dyn  = (const float*)d_in[1];
  const float* sW   = (const float*)d_in[2];
  const float* sb   = (const float*)d_in[3];
  const float* dW   = (const float*)d_in[4];
  const float* db   = (const float*)d_in[5];
  const float* x0   = (const float*)d_in[6];
  const float* h0   = (const float*)d_in[7];
  const float* Wemb = (const float*)d_in[8];
  const float* bemb = (const float*)d_in[9];
  const float* Wih  = (const float*)d_in[10];
  const float* Whh  = (const float*)d_in[11];
  const float* bih  = (const float*)d_in[12];
  const float* bhh  = (const float*)d_in[13];
  const float* Wa   = (const float*)d_in[14];
  const float* va   = (const float*)d_in[15];
  const float* Wd   = (const float*)d_in[16];
  const float* vd   = (const float*)d_in[17];
  float* out = (float*)d_out;

  k_decode<<<NB, 256, 0, stream>>>(stat, dyn, sW, sb, dW, db, x0, h0,
                                   Wemb, bemb, Wih, Whh, bih, bhh,
                                   Wa, va, Wd, vd, out);
}